// Round 4
// baseline (702.192 us; speedup 1.0000x reference)
//
#include <hip/hip_runtime.h>
#include <math.h>

// Problem constants
#define N_ROT 32      // 8 inclinations x 4 azimuths
#define O_CH 16
#define I_CH 8
#define KVOL 27
#define DHW 40
#define SPATIAL (DHW*DHW*DHW)        // 64000
#define OUT_PLANE (2*O_CH*SPATIAL)   // 2048000 elements per output tensor

// Reduction-order knob for the conv (hypothesis C = Eigen/XLA-CPU NDHWC):
//   1 -> (kz,ky,kx) outer, ci innermost, f32 fma chain   [current hypothesis]
//   0 -> ci outer, (kz,ky,kx) inner, f32 fma chain       [im2col-NCDHW fallback]
#define CI_INNERMOST 1

// ---------------------------------------------------------------------------
// Kernel 1: rotated weights wrot[o][p][ci][r], p = kz*9+ky*3+kx.
// Geometry in f64 (bit-matches numpy's T build; T entries rounded to f32 as
// in _TRANSFORMS.astype(np.float32)). Contraction over q emulates XLA f32
// dot: ascending q, fused multiply-add, single chain.
// One thread per (r, p).
// ---------------------------------------------------------------------------
__global__ void build_wrot(const float* __restrict__ w, float* __restrict__ wrot) {
    int tid = blockIdx.x * blockDim.x + threadIdx.x;
    if (tid >= N_ROT * KVOL) return;
    int r = tid / KVOL, p = tid % KVOL;
    int th = r / 4, ph = r % 4;
    double theta = ((double)th * 22.5) * (M_PI / 180.0);   // np.deg2rad
    double phi   = ((double)ph * 90.0) * (M_PI / 180.0);
    double ct = cos(theta), st = sin(theta);
    double cp = cos(phi),   sp = sin(phi);
    // R = Rz @ Ry
    double R00 = cp*ct, R01 = -sp, R02 = cp*st;
    double R10 = sp*ct, R11 =  cp, R12 = sp*st;
    double R20 = -st,   R21 = 0.0, R22 = ct;
    double d0 = (double)(p / 9) - 1.0;
    double d1 = (double)((p / 3) % 3) - 1.0;
    double d2 = (double)(p % 3) - 1.0;
    // src = (idx - c) @ R + c ; left-to-right order matches numpy dot
    double s0 = d0*R00 + d1*R10 + d2*R20 + 1.0;
    double s1 = d0*R01 + d1*R11 + d2*R21 + 1.0;
    double s2 = d0*R02 + d1*R12 + d2*R22 + 1.0;
    double f0 = floor(s0), f1 = floor(s1), f2 = floor(s2);
    double w0 = s0 - f0, w1 = s1 - f1, w2 = s2 - f2;
    int i0 = (int)f0, i1 = (int)f1, i2 = (int)f2;

    // Dense T row p in f32 (valid corners never collide -> single rounding,
    // identical bits to f64-accumulate-then-astype(float32)).
    float tq[KVOL];
    #pragma unroll
    for (int q = 0; q < KVOL; q++) tq[q] = 0.0f;

    for (int dz = 0; dz < 2; dz++)
      for (int dy = 0; dy < 2; dy++)
        for (int dx = 0; dx < 2; dx++) {
            int n0 = i0 + dz, n1 = i1 + dy, n2 = i2 + dx;
            bool valid = (n0 >= 0 && n0 < 3 && n1 >= 0 && n1 < 3 && n2 >= 0 && n2 < 3);
            double wt = (dz ? w0 : 1.0 - w0) * (dy ? w1 : 1.0 - w1) * (dx ? w2 : 1.0 - w2);
            int lin = n0 * 9 + n1 * 3 + n2;
            lin = lin < 0 ? 0 : (lin > 26 ? 26 : lin);   // np.clip
            if (valid) tq[lin] += (float)wt;
        }

    for (int o = 0; o < O_CH; o++) {
        for (int i = 0; i < I_CH; i++) {
            const float* wf = w + (o * I_CH + i) * KVOL;
            float acc = 0.0f;
            for (int q = 0; q < KVOL; q++)
                acc = fmaf(tq[q], wf[q], acc);   // f32 fma chain, ascending q
            wrot[((o * KVOL + p) * I_CH + i) * N_ROT + r] = acc;
        }
    }
}

// ---------------------------------------------------------------------------
// Kernel 2: conv3d reproducing XLA-CPU f32 semantics + argmax + epilogue.
// Per output voxel and rotation: acc_f32 over (kz,ky,kx,ci) ascending with
// fmaf (single dependent chain). Padding zeros are exact fma no-ops -> skip.
// Block = 256 threads = spatial tile 8(x) x 8(y) x 4(z); one voxel/thread.
// LDS weights for this o: [k][ci][r], all reads wave-uniform broadcasts.
// ---------------------------------------------------------------------------
__global__ __launch_bounds__(256) void conv_max_epi(
        const float* __restrict__ x,
        const float* __restrict__ wrot,
        float* __restrict__ out) {
    __shared__ float wlds[KVOL * I_CH * N_ROT];   // 6912 floats = 27648 B

    int blk = blockIdx.x;
    int tx = blk % 5; blk /= 5;
    int ty = blk % 5; blk /= 5;
    int tz = blk % 10; blk /= 10;
    int o  = blk % O_CH; blk /= O_CH;
    int b  = blk;

    const float* wsrc = wrot + o * (KVOL * I_CH * N_ROT);
    for (int i = threadIdx.x; i < KVOL * I_CH * N_ROT; i += 256)
        wlds[i] = wsrc[i];
    __syncthreads();

    int lt = threadIdx.x;
    int lx = lt & 7;
    int ly = (lt >> 3) & 7;
    int lz = lt >> 6;            // 0..3
    int xx = tx * 8 + lx;
    int yy = ty * 8 + ly;
    int zz = tz * 4 + lz;        // 0..39

    float acc[N_ROT];
    #pragma unroll
    for (int r = 0; r < N_ROT; r++) acc[r] = 0.0f;

    const float* xb = x + (size_t)b * I_CH * SPATIAL;

#if CI_INNERMOST
    #pragma unroll
    for (int kz = 0; kz < 3; kz++) {
        int zv = zz + kz - 1;
        bool zok = (zv >= 0 && zv < DHW);
        #pragma unroll
        for (int ky = 0; ky < 3; ky++) {
            int yv = yy + ky - 1;
            bool yok = (yv >= 0 && yv < DHW);
            #pragma unroll
            for (int kx = 0; kx < 3; kx++) {
                int xv = xx + kx - 1;
                bool ok = zok && yok && (xv >= 0 && xv < DHW);
                if (!ok) continue;               // exact no-op in the fma chain
                int k = kz * 9 + ky * 3 + kx;
                int sidx = (zv * DHW + yv) * DHW + xv;
                for (int ci = 0; ci < I_CH; ci++) {
                    float xval = xb[ci * SPATIAL + sidx];
                    const float* wp = &wlds[(k * I_CH + ci) * N_ROT];
                    #pragma unroll
                    for (int r = 0; r < N_ROT; r++)
                        acc[r] = fmaf(xval, wp[r], acc[r]);
                }
            }
        }
    }
#else
    for (int ci = 0; ci < I_CH; ci++) {
        #pragma unroll
        for (int kz = 0; kz < 3; kz++) {
            int zv = zz + kz - 1;
            bool zok = (zv >= 0 && zv < DHW);
            #pragma unroll
            for (int ky = 0; ky < 3; ky++) {
                int yv = yy + ky - 1;
                bool yok = (yv >= 0 && yv < DHW);
                #pragma unroll
                for (int kx = 0; kx < 3; kx++) {
                    int xv = xx + kx - 1;
                    bool ok = zok && yok && (xv >= 0 && xv < DHW);
                    if (!ok) continue;
                    int k = kz * 9 + ky * 3 + kx;
                    float xval = xb[ci * SPATIAL + (zv * DHW + yv) * DHW + xv];
                    const float* wp = &wlds[(k * I_CH + ci) * N_ROT];
                    #pragma unroll
                    for (int r = 0; r < N_ROT; r++)
                        acc[r] = fmaf(xval, wp[r], acc[r]);
                }
            }
        }
    }
#endif

    // epilogue (f32, like the reference): first-max argmax, relu, trig
    float best = acc[0]; int bi = 0;
    #pragma unroll
    for (int r = 1; r < N_ROT; r++)
        if (acc[r] > best) { best = acc[r]; bi = r; }
    float s = best > 0.0f ? best : 0.0f;
    float ang = (float)bi * (float)(M_PI / 4.0);
    float sa = sinf(ang), ca = cosf(ang);
    int oidx = ((b * O_CH + o) * SPATIAL) + (zz * DHW + yy) * DHW + xx;
    out[oidx]                 = s * sa * ca;
    out[oidx + OUT_PLANE]     = s * sa * sa;
    out[oidx + 2 * OUT_PLANE] = s * ca;
}

extern "C" void kernel_launch(void* const* d_in, const int* in_sizes, int n_in,
                              void* d_out, int out_size, void* d_ws, size_t ws_size,
                              hipStream_t stream) {
    const float* x = (const float*)d_in[0];      // [2,8,40,40,40]
    const float* w = (const float*)d_in[1];      // [16,8,3,3,3]
    float* out = (float*)d_out;                  // u,v,w concatenated
    float* wrot = (float*)d_ws;                  // [16][27][8][32] f32 = 442368 B

    build_wrot<<<(N_ROT * KVOL + 255) / 256, 256, 0, stream>>>(w, wrot);

    // grid: 5x5 xy-tiles * 10 z-tiles * 16 o * 2 b = 8000 blocks
    int grid = 5 * 5 * 10 * O_CH * 2;
    conv_max_epi<<<grid, 256, 0, stream>>>(x, wrot, out);
}

// Round 5
// 501.032 us; speedup vs baseline: 1.4015x; 1.4015x over previous
//
#include <hip/hip_runtime.h>
#include <math.h>

// Problem constants
#define N_ROT 32      // 8 inclinations x 4 azimuths
#define O_CH 16
#define I_CH 8
#define KVOL 27
#define DHW 40
#define SPATIAL (DHW*DHW*DHW)        // 64000
#define OUT_PLANE (2*O_CH*SPATIAL)   // 2048000 elements per output tensor

// ---------------------------------------------------------------------------
// Kernel 1: rotated weights wrot[o][p][ci][r], p = kz*9+ky*3+kx.
// Geometry in f64 (bit-matches numpy's T build; T entries rounded to f32 as
// in _TRANSFORMS.astype(np.float32)). Contraction over q emulates XLA f32
// dot: ascending q, fused multiply-add, single chain.  UNCHANGED from the
// passing R4 kernel — this bit pattern is load-bearing for the argmax.
// ---------------------------------------------------------------------------
__global__ void build_wrot(const float* __restrict__ w, float* __restrict__ wrot) {
    int tid = blockIdx.x * blockDim.x + threadIdx.x;
    if (tid >= N_ROT * KVOL) return;
    int r = tid / KVOL, p = tid % KVOL;
    int th = r / 4, ph = r % 4;
    double theta = ((double)th * 22.5) * (M_PI / 180.0);   // np.deg2rad
    double phi   = ((double)ph * 90.0) * (M_PI / 180.0);
    double ct = cos(theta), st = sin(theta);
    double cp = cos(phi),   sp = sin(phi);
    // R = Rz @ Ry
    double R00 = cp*ct, R01 = -sp, R02 = cp*st;
    double R10 = sp*ct, R11 =  cp, R12 = sp*st;
    double R20 = -st,   R21 = 0.0, R22 = ct;
    double d0 = (double)(p / 9) - 1.0;
    double d1 = (double)((p / 3) % 3) - 1.0;
    double d2 = (double)(p % 3) - 1.0;
    double s0 = d0*R00 + d1*R10 + d2*R20 + 1.0;
    double s1 = d0*R01 + d1*R11 + d2*R21 + 1.0;
    double s2 = d0*R02 + d1*R12 + d2*R22 + 1.0;
    double f0 = floor(s0), f1 = floor(s1), f2 = floor(s2);
    double w0 = s0 - f0, w1 = s1 - f1, w2 = s2 - f2;
    int i0 = (int)f0, i1 = (int)f1, i2 = (int)f2;

    float tq[KVOL];
    #pragma unroll
    for (int q = 0; q < KVOL; q++) tq[q] = 0.0f;

    for (int dz = 0; dz < 2; dz++)
      for (int dy = 0; dy < 2; dy++)
        for (int dx = 0; dx < 2; dx++) {
            int n0 = i0 + dz, n1 = i1 + dy, n2 = i2 + dx;
            bool valid = (n0 >= 0 && n0 < 3 && n1 >= 0 && n1 < 3 && n2 >= 0 && n2 < 3);
            double wt = (dz ? w0 : 1.0 - w0) * (dy ? w1 : 1.0 - w1) * (dx ? w2 : 1.0 - w2);
            int lin = n0 * 9 + n1 * 3 + n2;
            lin = lin < 0 ? 0 : (lin > 26 ? 26 : lin);   // np.clip
            if (valid) tq[lin] += (float)wt;
        }

    for (int o = 0; o < O_CH; o++) {
        for (int i = 0; i < I_CH; i++) {
            const float* wf = w + (o * I_CH + i) * KVOL;
            float acc = 0.0f;
            for (int q = 0; q < KVOL; q++)
                acc = fmaf(tq[q], wf[q], acc);   // f32 fma chain, ascending q
            wrot[((o * KVOL + p) * I_CH + i) * N_ROT + r] = acc;
        }
    }
}

// ---------------------------------------------------------------------------
// Kernel 2: conv3d with XLA-CPU-identical f32 fma chains + argmax + epilogue.
// Each thread now computes FOUR consecutive z-voxels so each 128B LDS weight
// read feeds 128 FMAs (was 32): DS pipe 96cyc vs VALU 256cyc per (k,ci).
// Per-voxel chain order (kz,ky,kx,ci ascending, fmaf) is bit-identical to the
// passing R4 kernel; out-of-bounds taps contribute fmaf(0,w,acc)==acc exactly
// (acc can never be -0 in an accumulation chain starting from +0).
// Block = 128 threads = 8(x) x 8(y) x 2(lz); thread covers z = zb..zb+3.
// Grid 5x5x5 tiles x 16 o x 2 b = 4000 blocks, no partial tiles (40 = 5*8).
// ---------------------------------------------------------------------------
__global__ __launch_bounds__(128) void conv_max_epi(
        const float* __restrict__ x,
        const float* __restrict__ wrot,
        float* __restrict__ out) {
    __shared__ float wlds[KVOL * I_CH * N_ROT];   // 6912 floats = 27648 B

    int blk = blockIdx.x;
    int tx = blk % 5; blk /= 5;
    int ty = blk % 5; blk /= 5;
    int tz = blk % 5; blk /= 5;
    int o  = blk % O_CH; blk /= O_CH;
    int b  = blk;

    // stage this o's weights (vectorized)
    {
        const float4* ws4 = (const float4*)(wrot + o * (KVOL * I_CH * N_ROT));
        float4* wl4 = (float4*)wlds;
        for (int i = threadIdx.x; i < KVOL * I_CH * N_ROT / 4; i += 128)
            wl4[i] = ws4[i];
    }
    __syncthreads();

    int lt = threadIdx.x;
    int lx = lt & 7;
    int ly = (lt >> 3) & 7;
    int lz = lt >> 6;                 // 0..1
    int xx = tx * 8 + lx;
    int yy = ty * 8 + ly;
    int zb = tz * 8 + lz * 4;         // voxels zb..zb+3, always in [0,40)

    float acc[4][N_ROT];
    #pragma unroll
    for (int v = 0; v < 4; v++)
        #pragma unroll
        for (int r = 0; r < N_ROT; r++) acc[v][r] = 0.0f;

    const float* xb = x + (size_t)b * I_CH * SPATIAL;

    #pragma clang loop unroll(disable)
    for (int k = 0; k < KVOL; k++) {
        int kz = k / 9, ky = (k / 3) % 3, kx = k % 3;
        int z0 = zb + kz - 1;                 // voxel v reads z0+v
        int yv = yy + ky - 1;
        int xv = xx + kx - 1;
        bool xyok = ((unsigned)yv < DHW) && ((unsigned)xv < DHW);
        int sbase = (z0 * DHW + yv) * DHW + xv;

        bool ok4[4]; int off4[4];
        #pragma unroll
        for (int v = 0; v < 4; v++) {
            ok4[v] = xyok && ((unsigned)(z0 + v) < DHW);
            off4[v] = sbase + v * (DHW * DHW);
        }

        const float* wk = &wlds[k * I_CH * N_ROT];

        #pragma clang loop unroll(disable)
        for (int ci = 0; ci < I_CH; ci++) {
            const float* xc = xb + ci * SPATIAL;
            float xvv[4];
            #pragma unroll
            for (int v = 0; v < 4; v++)
                xvv[v] = ok4[v] ? xc[off4[v]] : 0.0f;

            const float* wp = wk + ci * N_ROT;
            #pragma unroll
            for (int r = 0; r < N_ROT; r++) {
                float wv = wp[r];
                #pragma unroll
                for (int v = 0; v < 4; v++)
                    acc[v][r] = fmaf(xvv[v], wv, acc[v][r]);
            }
        }
    }

    // epilogue (bit-identical to R4): first-max argmax, relu, trig
    #pragma unroll
    for (int v = 0; v < 4; v++) {
        float best = acc[v][0]; int bi = 0;
        #pragma unroll
        for (int r = 1; r < N_ROT; r++)
            if (acc[v][r] > best) { best = acc[v][r]; bi = r; }
        float s = best > 0.0f ? best : 0.0f;
        float ang = (float)bi * (float)(M_PI / 4.0);
        float sa = sinf(ang), ca = cosf(ang);
        int oidx = ((b * O_CH + o) * SPATIAL) + ((zb + v) * DHW + yy) * DHW + xx;
        out[oidx]                 = s * sa * ca;
        out[oidx + OUT_PLANE]     = s * sa * sa;
        out[oidx + 2 * OUT_PLANE] = s * ca;
    }
}

extern "C" void kernel_launch(void* const* d_in, const int* in_sizes, int n_in,
                              void* d_out, int out_size, void* d_ws, size_t ws_size,
                              hipStream_t stream) {
    const float* x = (const float*)d_in[0];      // [2,8,40,40,40]
    const float* w = (const float*)d_in[1];      // [16,8,3,3,3]
    float* out = (float*)d_out;                  // u,v,w concatenated
    float* wrot = (float*)d_ws;                  // [16][27][8][32] f32 = 442368 B

    build_wrot<<<(N_ROT * KVOL + 255) / 256, 256, 0, stream>>>(w, wrot);

    // grid: 5x5x5 tiles * 16 o * 2 b = 4000 blocks of 128 threads
    int grid = 5 * 5 * 5 * O_CH * 2;
    conv_max_epi<<<grid, 128, 0, stream>>>(x, wrot, out);
}

// Round 6
// 474.168 us; speedup vs baseline: 1.4809x; 1.0567x over previous
//
#include <hip/hip_runtime.h>
#include <math.h>

// Problem constants
#define N_ROT 32      // 8 inclinations x 4 azimuths
#define O_CH 16
#define I_CH 8
#define KVOL 27
#define DHW 40
#define SPATIAL (DHW*DHW*DHW)        // 64000
#define OUT_PLANE (2*O_CH*SPATIAL)   // 2048000 elements per output tensor
#define PDHW 42
#define PSPAT (PDHW*PDHW*PDHW)       // 74088 padded spatial
#define WROT_ELEMS (O_CH*KVOL*I_CH*N_ROT)   // 110592 floats = 442368 B
#define XPAD_ELEMS (2*I_CH*PSPAT)           // 1185408 floats = 4741632 B

// ---------------------------------------------------------------------------
// Kernel 1: rotated weights wrot[o][p][ci][r], p = kz*9+ky*3+kx.
// UNCHANGED from the passing R4/R5 kernel — bit pattern is load-bearing.
// ---------------------------------------------------------------------------
__global__ void build_wrot(const float* __restrict__ w, float* __restrict__ wrot) {
    int tid = blockIdx.x * blockDim.x + threadIdx.x;
    if (tid >= N_ROT * KVOL) return;
    int r = tid / KVOL, p = tid % KVOL;
    int th = r / 4, ph = r % 4;
    double theta = ((double)th * 22.5) * (M_PI / 180.0);   // np.deg2rad
    double phi   = ((double)ph * 90.0) * (M_PI / 180.0);
    double ct = cos(theta), st = sin(theta);
    double cp = cos(phi),   sp = sin(phi);
    double R00 = cp*ct, R01 = -sp, R02 = cp*st;
    double R10 = sp*ct, R11 =  cp, R12 = sp*st;
    double R20 = -st,   R21 = 0.0, R22 = ct;
    double d0 = (double)(p / 9) - 1.0;
    double d1 = (double)((p / 3) % 3) - 1.0;
    double d2 = (double)(p % 3) - 1.0;
    double s0 = d0*R00 + d1*R10 + d2*R20 + 1.0;
    double s1 = d0*R01 + d1*R11 + d2*R21 + 1.0;
    double s2 = d0*R02 + d1*R12 + d2*R22 + 1.0;
    double f0 = floor(s0), f1 = floor(s1), f2 = floor(s2);
    double w0 = s0 - f0, w1 = s1 - f1, w2 = s2 - f2;
    int i0 = (int)f0, i1 = (int)f1, i2 = (int)f2;

    float tq[KVOL];
    #pragma unroll
    for (int q = 0; q < KVOL; q++) tq[q] = 0.0f;

    for (int dz = 0; dz < 2; dz++)
      for (int dy = 0; dy < 2; dy++)
        for (int dx = 0; dx < 2; dx++) {
            int n0 = i0 + dz, n1 = i1 + dy, n2 = i2 + dx;
            bool valid = (n0 >= 0 && n0 < 3 && n1 >= 0 && n1 < 3 && n2 >= 0 && n2 < 3);
            double wt = (dz ? w0 : 1.0 - w0) * (dy ? w1 : 1.0 - w1) * (dx ? w2 : 1.0 - w2);
            int lin = n0 * 9 + n1 * 3 + n2;
            lin = lin < 0 ? 0 : (lin > 26 ? 26 : lin);   // np.clip
            if (valid) tq[lin] += (float)wt;
        }

    for (int o = 0; o < O_CH; o++) {
        for (int i = 0; i < I_CH; i++) {
            const float* wf = w + (o * I_CH + i) * KVOL;
            float acc = 0.0f;
            for (int q = 0; q < KVOL; q++)
                acc = fmaf(tq[q], wf[q], acc);   // f32 fma chain, ascending q
            wrot[((o * KVOL + p) * I_CH + i) * N_ROT + r] = acc;
        }
    }
}

// ---------------------------------------------------------------------------
// Kernel 1b: zero-pad x (2,8,40^3) -> xp (2,8,42^3). Padding value is +0.0f,
// so padded taps are exact fma no-ops (proven chain-neutral: R4 skip vs R5
// include-zero were bit-identical).
// ---------------------------------------------------------------------------
__global__ void pad_x(const float* __restrict__ x, float* __restrict__ xp) {
    int idx = blockIdx.x * blockDim.x + threadIdx.x;
    if (idx >= XPAD_ELEMS) return;
    int s = idx % PSPAT;
    int bc = idx / PSPAT;
    int xpp = s % PDHW;
    int ypp = (s / PDHW) % PDHW;
    int zpp = s / (PDHW * PDHW);
    float v = 0.0f;
    if (xpp >= 1 && xpp <= DHW && ypp >= 1 && ypp <= DHW && zpp >= 1 && zpp <= DHW)
        v = x[bc * SPATIAL + ((zpp - 1) * DHW + (ypp - 1)) * DHW + (xpp - 1)];
    xp[idx] = v;
}

// ---------------------------------------------------------------------------
// Kernel 2: conv3d with XLA-CPU-identical f32 fma chains + argmax + epilogue.
// 256 threads/block = 8(x) x 8(y) x 4(lz), 2 z-voxels per thread.
// Per-voxel chain (kz,ky,kx,ci ascending, fmaf) bit-identical to R4/R5.
// PADDED=true reads the 42^3 zero-padded x (no bounds logic at all).
// ---------------------------------------------------------------------------
template<bool PADDED>
__global__ __launch_bounds__(256, 4) void conv_max_epi(
        const float* __restrict__ xg,
        const float* __restrict__ wrot,
        float* __restrict__ out) {
    __shared__ float wlds[KVOL * I_CH * N_ROT];   // 6912 floats = 27648 B

    int blk = blockIdx.x;
    int tx = blk % 5; blk /= 5;
    int ty = blk % 5; blk /= 5;
    int tz = blk % 5; blk /= 5;
    int o  = blk % O_CH; blk /= O_CH;
    int b  = blk;

    // stage this o's weights (vectorized)
    {
        const float4* ws4 = (const float4*)(wrot + o * (KVOL * I_CH * N_ROT));
        float4* wl4 = (float4*)wlds;
        for (int i = threadIdx.x; i < KVOL * I_CH * N_ROT / 4; i += 256)
            wl4[i] = ws4[i];
    }
    __syncthreads();

    int lt = threadIdx.x;
    int lx = lt & 7;
    int ly = (lt >> 3) & 7;
    int lz = lt >> 6;                 // 0..3
    int xx = tx * 8 + lx;
    int yy = ty * 8 + ly;
    int zb = tz * 8 + lz * 2;         // voxels zb, zb+1

    float acc0[N_ROT], acc1[N_ROT];
    #pragma unroll
    for (int r = 0; r < N_ROT; r++) { acc0[r] = 0.0f; acc1[r] = 0.0f; }

    const float* xb = xg + (size_t)b * I_CH * (PADDED ? PSPAT : SPATIAL);

    #pragma clang loop unroll(disable)
    for (int k = 0; k < KVOL; k++) {
        int kz = k / 9, ky = (k / 3) % 3, kx = k % 3;
        const float* wk = &wlds[k * I_CH * N_ROT];

        if (PADDED) {
            // padded coords: z0 = zb+kz-1 -> zp = zb+kz, etc.
            int sbase = ((zb + kz) * PDHW + (yy + ky)) * PDHW + (xx + kx);
            #pragma clang loop unroll(disable)
            for (int ci = 0; ci < I_CH; ci++) {
                const float* xc = xb + ci * PSPAT;
                float x0 = xc[sbase];
                float x1 = xc[sbase + PDHW * PDHW];
                const float* wp = wk + ci * N_ROT;
                #pragma unroll
                for (int r = 0; r < N_ROT; r++) {
                    float wv = wp[r];
                    acc0[r] = fmaf(x0, wv, acc0[r]);
                    acc1[r] = fmaf(x1, wv, acc1[r]);
                }
            }
        } else {
            int z0 = zb + kz - 1;
            int yv = yy + ky - 1;
            int xv = xx + kx - 1;
            bool xyok = ((unsigned)yv < DHW) && ((unsigned)xv < DHW);
            bool ok0 = xyok && ((unsigned)z0 < DHW);
            bool ok1 = xyok && ((unsigned)(z0 + 1) < DHW);
            int sbase = (z0 * DHW + yv) * DHW + xv;
            #pragma clang loop unroll(disable)
            for (int ci = 0; ci < I_CH; ci++) {
                const float* xc = xb + ci * SPATIAL;
                float x0 = ok0 ? xc[sbase] : 0.0f;
                float x1 = ok1 ? xc[sbase + DHW * DHW] : 0.0f;
                const float* wp = wk + ci * N_ROT;
                #pragma unroll
                for (int r = 0; r < N_ROT; r++) {
                    float wv = wp[r];
                    acc0[r] = fmaf(x0, wv, acc0[r]);
                    acc1[r] = fmaf(x1, wv, acc1[r]);
                }
            }
        }
    }

    // epilogue (bit-identical to R4/R5): first-max argmax, relu, trig
    #pragma unroll
    for (int v = 0; v < 2; v++) {
        const float* a = v ? acc1 : acc0;
        float best = a[0]; int bi = 0;
        #pragma unroll
        for (int r = 1; r < N_ROT; r++)
            if (a[r] > best) { best = a[r]; bi = r; }
        float s = best > 0.0f ? best : 0.0f;
        float ang = (float)bi * (float)(M_PI / 4.0);
        float sa = sinf(ang), ca = cosf(ang);
        int oidx = ((b * O_CH + o) * SPATIAL) + ((zb + v) * DHW + yy) * DHW + xx;
        out[oidx]                 = s * sa * ca;
        out[oidx + OUT_PLANE]     = s * sa * sa;
        out[oidx + 2 * OUT_PLANE] = s * ca;
    }
}

extern "C" void kernel_launch(void* const* d_in, const int* in_sizes, int n_in,
                              void* d_out, int out_size, void* d_ws, size_t ws_size,
                              hipStream_t stream) {
    const float* x = (const float*)d_in[0];      // [2,8,40,40,40]
    const float* w = (const float*)d_in[1];      // [16,8,3,3,3]
    float* out = (float*)d_out;                  // u,v,w concatenated
    float* wrot = (float*)d_ws;                  // [16][27][8][32] f32

    const size_t wrot_bytes = (size_t)WROT_ELEMS * 4;
    const size_t need = wrot_bytes + (size_t)XPAD_ELEMS * 4;

    build_wrot<<<(N_ROT * KVOL + 255) / 256, 256, 0, stream>>>(w, wrot);

    int grid = 5 * 5 * 5 * O_CH * 2;   // 4000 blocks of 256 threads

    if (ws_size >= need) {
        float* xp = (float*)((char*)d_ws + wrot_bytes);
        pad_x<<<(XPAD_ELEMS + 255) / 256, 256, 0, stream>>>(x, xp);
        conv_max_epi<true><<<grid, 256, 0, stream>>>(xp, wrot, out);
    } else {
        conv_max_epi<false><<<grid, 256, 0, stream>>>(x, wrot, out);
    }
}

// Round 7
// 338.699 us; speedup vs baseline: 2.0732x; 1.4000x over previous
//
#include <hip/hip_runtime.h>
#include <math.h>

// Problem constants
#define N_ROT 32      // 8 inclinations x 4 azimuths
#define O_CH 16
#define I_CH 8
#define KVOL 27
#define DHW 40
#define SPATIAL (DHW*DHW*DHW)        // 64000
#define OUT_PLANE (2*O_CH*SPATIAL)   // 2048000 elements per output tensor
#define PDHW 42
#define PSPAT (PDHW*PDHW*PDHW)       // 74088 padded spatial
#define WROT_ELEMS (O_CH*KVOL*I_CH*N_ROT)   // 110592 floats = 442368 B
#define XPAD_ELEMS (2*PSPAT*I_CH)           // NDHWC padded: 1185408 floats

// ---------------------------------------------------------------------------
// Kernel 1: rotated weights wrot[o][k][ci][r], k = kz*9+ky*3+kx.
// UNCHANGED from the passing R4-R6 kernels — bit pattern is load-bearing.
// ---------------------------------------------------------------------------
__global__ void build_wrot(const float* __restrict__ w, float* __restrict__ wrot) {
    int tid = blockIdx.x * blockDim.x + threadIdx.x;
    if (tid >= N_ROT * KVOL) return;
    int r = tid / KVOL, p = tid % KVOL;
    int th = r / 4, ph = r % 4;
    double theta = ((double)th * 22.5) * (M_PI / 180.0);   // np.deg2rad
    double phi   = ((double)ph * 90.0) * (M_PI / 180.0);
    double ct = cos(theta), st = sin(theta);
    double cp = cos(phi),   sp = sin(phi);
    double R00 = cp*ct, R01 = -sp, R02 = cp*st;
    double R10 = sp*ct, R11 =  cp, R12 = sp*st;
    double R20 = -st,   R21 = 0.0, R22 = ct;
    double d0 = (double)(p / 9) - 1.0;
    double d1 = (double)((p / 3) % 3) - 1.0;
    double d2 = (double)(p % 3) - 1.0;
    double s0 = d0*R00 + d1*R10 + d2*R20 + 1.0;
    double s1 = d0*R01 + d1*R11 + d2*R21 + 1.0;
    double s2 = d0*R02 + d1*R12 + d2*R22 + 1.0;
    double f0 = floor(s0), f1 = floor(s1), f2 = floor(s2);
    double w0 = s0 - f0, w1 = s1 - f1, w2 = s2 - f2;
    int i0 = (int)f0, i1 = (int)f1, i2 = (int)f2;

    float tq[KVOL];
    #pragma unroll
    for (int q = 0; q < KVOL; q++) tq[q] = 0.0f;

    for (int dz = 0; dz < 2; dz++)
      for (int dy = 0; dy < 2; dy++)
        for (int dx = 0; dx < 2; dx++) {
            int n0 = i0 + dz, n1 = i1 + dy, n2 = i2 + dx;
            bool valid = (n0 >= 0 && n0 < 3 && n1 >= 0 && n1 < 3 && n2 >= 0 && n2 < 3);
            double wt = (dz ? w0 : 1.0 - w0) * (dy ? w1 : 1.0 - w1) * (dx ? w2 : 1.0 - w2);
            int lin = n0 * 9 + n1 * 3 + n2;
            lin = lin < 0 ? 0 : (lin > 26 ? 26 : lin);   // np.clip
            if (valid) tq[lin] += (float)wt;
        }

    for (int o = 0; o < O_CH; o++) {
        for (int i = 0; i < I_CH; i++) {
            const float* wf = w + (o * I_CH + i) * KVOL;
            float acc = 0.0f;
            for (int q = 0; q < KVOL; q++)
                acc = fmaf(tq[q], wf[q], acc);   // f32 fma chain, ascending q
            wrot[((o * KVOL + p) * I_CH + i) * N_ROT + r] = acc;
        }
    }
}

// ---------------------------------------------------------------------------
// Kernel 1b: zero-pad + transpose x (NCDHW 40^3) -> xp (NDHWC 42^3):
// xp[b][zp][yp][xp][ci]. Padding +0.0f = exact fma no-op (proven R4 vs R5).
// ---------------------------------------------------------------------------
__global__ void pad_x(const float* __restrict__ x, float* __restrict__ xp) {
    int idx = blockIdx.x * blockDim.x + threadIdx.x;
    if (idx >= XPAD_ELEMS) return;
    int ci = idx & 7;
    int s  = (idx >> 3) % PSPAT;
    int b  = idx / (8 * PSPAT);
    int xq = s % PDHW;
    int yq = (s / PDHW) % PDHW;
    int zq = s / (PDHW * PDHW);
    float v = 0.0f;
    if (xq >= 1 && xq <= DHW && yq >= 1 && yq <= DHW && zq >= 1 && zq <= DHW)
        v = x[((b * I_CH + ci) * SPATIAL) + ((zq - 1) * DHW + (yq - 1)) * DHW + (xq - 1)];
    xp[idx] = v;
}

// ---------------------------------------------------------------------------
// Kernel 2: conv3d with XLA-CPU-identical f32 fma chains + argmax + epilogue.
// No LDS. Weights read via wave-uniform indices -> compiler scalarizes to
// s_load (SMEM pipe); v_fma consumes the SGPR operand directly. x read as
// two float4 per voxel per tap from the padded NDHWC tensor.
// 256 threads/block = 8(x) x 8(y) x 4(lz), 2 z-voxels per thread.
// Per-voxel chain (kz,ky,kx,ci ascending, fmaf) bit-identical to R4-R6.
// ---------------------------------------------------------------------------
template<bool PADDED>
__global__ __launch_bounds__(256, 4) void conv_max_epi(
        const float* __restrict__ xg,
        const float* __restrict__ wrot,
        float* __restrict__ out) {
    int blk = blockIdx.x;
    int tx = blk % 5; blk /= 5;
    int ty = blk % 5; blk /= 5;
    int tz = blk % 5; blk /= 5;
    int o  = blk % O_CH; blk /= O_CH;
    int b  = blk;

    int lt = threadIdx.x;
    int lx = lt & 7;
    int ly = (lt >> 3) & 7;
    int lz = lt >> 6;                 // 0..3
    int xx = tx * 8 + lx;
    int yy = ty * 8 + ly;
    int zb = tz * 8 + lz * 2;         // voxels zb, zb+1

    float acc0[N_ROT], acc1[N_ROT];
    #pragma unroll
    for (int r = 0; r < N_ROT; r++) { acc0[r] = 0.0f; acc1[r] = 0.0f; }

    const float* __restrict__ wo = wrot + o * (KVOL * I_CH * N_ROT);

    if (PADDED) {
        const float* __restrict__ xb = xg + (size_t)b * (8 * PSPAT);
        #pragma clang loop unroll(disable)
        for (int k = 0; k < KVOL; k++) {
            int kz = k / 9, ky = (k / 3) % 3, kx = k % 3;
            int sb = ((zb + kz) * PDHW + (yy + ky)) * PDHW + (xx + kx);
            const float4* p0 = (const float4*)(xb + (size_t)sb * 8);
            const float4* p1 = (const float4*)(xb + ((size_t)sb + PDHW * PDHW) * 8);
            float4 a0 = p0[0], a1 = p0[1];       // voxel zb:   ci 0-3, 4-7
            float4 b0 = p1[0], b1 = p1[1];       // voxel zb+1: ci 0-3, 4-7
            float xv0[8] = {a0.x, a0.y, a0.z, a0.w, a1.x, a1.y, a1.z, a1.w};
            float xv1[8] = {b0.x, b0.y, b0.z, b0.w, b1.x, b1.y, b1.z, b1.w};
            const float* __restrict__ wk = wo + k * (I_CH * N_ROT);
            #pragma unroll
            for (int ci = 0; ci < I_CH; ci++) {
                const float* __restrict__ wp = wk + ci * N_ROT;
                float x0 = xv0[ci], x1 = xv1[ci];
                #pragma unroll
                for (int r = 0; r < N_ROT; r++) {
                    float wv = wp[r];            // wave-uniform -> s_load
                    acc0[r] = fmaf(x0, wv, acc0[r]);
                    acc1[r] = fmaf(x1, wv, acc1[r]);
                }
            }
        }
    } else {
        // fallback (ws too small): bounds-checked NCDHW, same fma chains
        const float* __restrict__ xb = xg + (size_t)b * I_CH * SPATIAL;
        #pragma clang loop unroll(disable)
        for (int k = 0; k < KVOL; k++) {
            int kz = k / 9, ky = (k / 3) % 3, kx = k % 3;
            int z0 = zb + kz - 1;
            int yv = yy + ky - 1;
            int xv = xx + kx - 1;
            bool xyok = ((unsigned)yv < DHW) && ((unsigned)xv < DHW);
            bool ok0 = xyok && ((unsigned)z0 < DHW);
            bool ok1 = xyok && ((unsigned)(z0 + 1) < DHW);
            int sbase = (z0 * DHW + yv) * DHW + xv;
            const float* __restrict__ wk = wo + k * (I_CH * N_ROT);
            #pragma clang loop unroll(disable)
            for (int ci = 0; ci < I_CH; ci++) {
                const float* xc = xb + ci * SPATIAL;
                float x0 = ok0 ? xc[sbase] : 0.0f;
                float x1 = ok1 ? xc[sbase + DHW * DHW] : 0.0f;
                const float* __restrict__ wp = wk + ci * N_ROT;
                #pragma unroll
                for (int r = 0; r < N_ROT; r++) {
                    float wv = wp[r];
                    acc0[r] = fmaf(x0, wv, acc0[r]);
                    acc1[r] = fmaf(x1, wv, acc1[r]);
                }
            }
        }
    }

    // epilogue (bit-identical to R4-R6): first-max argmax, relu, trig
    #pragma unroll
    for (int v = 0; v < 2; v++) {
        const float* a = v ? acc1 : acc0;
        float best = a[0]; int bi = 0;
        #pragma unroll
        for (int r = 1; r < N_ROT; r++)
            if (a[r] > best) { best = a[r]; bi = r; }
        float s = best > 0.0f ? best : 0.0f;
        float ang = (float)bi * (float)(M_PI / 4.0);
        float sa = sinf(ang), ca = cosf(ang);
        int oidx = ((b * O_CH + o) * SPATIAL) + ((zb + v) * DHW + yy) * DHW + xx;
        out[oidx]                 = s * sa * ca;
        out[oidx + OUT_PLANE]     = s * sa * sa;
        out[oidx + 2 * OUT_PLANE] = s * ca;
    }
}

extern "C" void kernel_launch(void* const* d_in, const int* in_sizes, int n_in,
                              void* d_out, int out_size, void* d_ws, size_t ws_size,
                              hipStream_t stream) {
    const float* x = (const float*)d_in[0];      // [2,8,40,40,40]
    const float* w = (const float*)d_in[1];      // [16,8,3,3,3]
    float* out = (float*)d_out;                  // u,v,w concatenated
    float* wrot = (float*)d_ws;                  // [16][27][8][32] f32

    const size_t wrot_bytes = (size_t)WROT_ELEMS * 4;
    const size_t need = wrot_bytes + (size_t)XPAD_ELEMS * 4;

    build_wrot<<<(N_ROT * KVOL + 255) / 256, 256, 0, stream>>>(w, wrot);

    int grid = 5 * 5 * 5 * O_CH * 2;   // 4000 blocks of 256 threads

    if (ws_size >= need) {
        float* xp = (float*)((char*)d_ws + wrot_bytes);
        pad_x<<<(XPAD_ELEMS + 255) / 256, 256, 0, stream>>>(x, xp);
        conv_max_epi<true><<<grid, 256, 0, stream>>>(xp, wrot, out);
    } else {
        conv_max_epi<false><<<grid, 256, 0, stream>>>(x, wrot, out);
    }
}